// Round 1
// baseline (199.542 us; speedup 1.0000x reference)
//
#include <hip/hip_runtime.h>

// AWGN index channel: rx = idx XOR bitflip-mask(u < BER), then codebook gather,
// concat [fine | coarse] per batch row. Exact integer semantics -> absmax 0.
//
// Shapes: idx_c [64,32,32], idx_f [64,64,64], cb_c/cb_f [512,128] f32,
// u_c [64,32,32,9], u_f [64,64,64,9]. Out [64, 64*64*128 + 32*32*128] f32.

constexpr int   BITS       = 9;
constexpr float BER        = 0.02f;
constexpr int   Bn         = 64;
constexpr int   HC = 32, WC = 32, HF = 64, WF = 64, D = 128;
constexpr int   NF         = Bn * HF * WF;     // 262144 fine symbols
constexpr int   NC         = Bn * HC * WC;     // 65536 coarse symbols
constexpr int   NTOT       = NF + NC;          // 327680
constexpr int   FINE_ROW   = HF * WF * D;      // 524288 floats
constexpr int   COARSE_ROW = HC * WC * D;      // 131072 floats
constexpr int   ROW        = FINE_ROW + COARSE_ROW; // 655360 floats per batch row

// 8 symbols per 256-thread block: 32 lanes x float4 = 128 floats per symbol.
// NF % 8 == 0, so every block is purely fine or purely coarse.
__global__ __launch_bounds__(256) void chan_gather_kernel(
    const int*   __restrict__ idx_c,
    const int*   __restrict__ idx_f,
    const float* __restrict__ cb_c,
    const float* __restrict__ cb_f,
    const float* __restrict__ u_c,
    const float* __restrict__ u_f,
    float*       __restrict__ out)
{
    __shared__ int s_row[8];    // received (post-flip) codebook row
    __shared__ int s_off[8];    // output offset in floats (max 41.9M, fits int)
    __shared__ int s_coarse[8]; // which codebook

    const int t   = threadIdx.x;
    const int blk = blockIdx.x;

    if (t < 8) {
        const int i = blk * 8 + t;
        int v, off, coarse;
        const float* u;
        if (i < NF) {
            const int b   = i >> 12;        // / (HF*WF = 4096)
            const int rem = i & 4095;
            off    = b * ROW + rem * D;
            v      = idx_f[i];
            u      = u_f + (size_t)i * BITS;
            coarse = 0;
        } else {
            const int j   = i - NF;
            const int b   = j >> 10;        // / (HC*WC = 1024)
            const int rem = j & 1023;
            off    = b * ROW + FINE_ROW + rem * D;
            v      = idx_c[j];
            u      = u_c + (size_t)j * BITS;
            coarse = 1;
        }
        int flip = 0;
        #pragma unroll
        for (int k = 0; k < BITS; ++k)
            flip |= (u[k] < BER) ? (1 << k) : 0;
        s_row[t]    = (v ^ flip) & 511;     // clip is a no-op; mask is free
        s_off[t]    = off;
        s_coarse[t] = coarse;
    }
    __syncthreads();

    const int g    = t >> 5;   // symbol within block
    const int lane = t & 31;   // float4 slot within the 128-float row
    const float* cb = s_coarse[g] ? cb_c : cb_f;   // 256 KB each -> L2-resident
    const float4 val = ((const float4*)(cb + s_row[g] * D))[lane];
    ((float4*)(out + s_off[g]))[lane] = val;       // 512 B contiguous per symbol
}

extern "C" void kernel_launch(void* const* d_in, const int* in_sizes, int n_in,
                              void* d_out, int out_size, void* d_ws, size_t ws_size,
                              hipStream_t stream) {
    const int*   idx_c = (const int*)  d_in[0];
    const int*   idx_f = (const int*)  d_in[1];
    const float* cb_c  = (const float*)d_in[2];
    const float* cb_f  = (const float*)d_in[3];
    const float* u_c   = (const float*)d_in[4];
    const float* u_f   = (const float*)d_in[5];
    float*       out   = (float*)d_out;

    chan_gather_kernel<<<NTOT / 8, 256, 0, stream>>>(
        idx_c, idx_f, cb_c, cb_f, u_c, u_f, out);
}